// Round 1
// baseline (873.309 us; speedup 1.0000x reference)
//
#include <hip/hip_runtime.h>
#include <math.h>

#define B 32
#define NBOX 24564
#define NCLS 81
#define ROWLEN 93
#define CONF_T 0.5f
#define IOU_T 0.35f
#define NUM_PRED 10
#define IMG_W 512.0f
#define IMG_H 512.0f

#define BPB 64                                   // boxes per block in decode
#define K1_THREADS 256
#define NBLK ((NBOX + BPB - 1) / BPB)            // 384 blocks per image

#define K2T 1024
#define NPER_R 12                                // register-resident slots/thread
#define CAP_SLOTS (K2T * NPER_R)                 // 12288 candidates fast-path
#define NPER_ALL ((NBOX + K2T - 1) / K2T)        // 24 (full coverage)
#define NPER_OV (NPER_ALL - NPER_R)              // 12 overflow slots -> LDS

// ---------------- Kernel 1: decode + class argmax + COMPACTION --------------
// 256 threads / 64 boxes. Stage 64*93 floats via float4 (16B-aligned chunks),
// 4 lanes/box reduce the 81-class argmax. Valid candidates (cls!=0, score>=T)
// are appended to per-image compacted lists via wave-aggregated atomicAdd
// (one atomic per wave). Invalid boxes write NOTHING.
__global__ __launch_bounds__(K1_THREADS) void decode_kernel(
    const float* __restrict__ y, float4* __restrict__ cboxes,
    float* __restrict__ cscores, float* __restrict__ cclsid,
    int* __restrict__ cnt)
{
    __shared__ float4 lds4[(BPB * ROWLEN) / 4];  // 1488 float4 = 23808 B
    float* lds = (float*)lds4;
    int bid  = blockIdx.x;
    int b    = bid / NBLK;
    int blk  = bid % NBLK;
    int box0 = blk * BPB;
    int nb   = NBOX - box0; if (nb > BPB) nb = BPB;   // 64 or 52 (both %4==0)
    int n4   = (nb * ROWLEN) / 4;
    const float4* src = (const float4*)(y + ((size_t)b * NBOX + box0) * ROWLEN);
    for (int k = threadIdx.x; k < n4; k += K1_THREADS)
        lds4[k] = src[k];
    __syncthreads();

    int q  = threadIdx.x & 3;                    // lane quad within a box
    int bl = threadIdx.x >> 2;                   // local box index
    if (bl >= nb) return;                        // quad-aligned: waves stay sane
    const float* row = &lds[bl * ROWLEN];

    // strided partial argmax; strict '>' keeps first occurrence per lane
    float best = -INFINITY; int bci = 0x7fffffff;
    for (int c = q; c < NCLS; c += 4) {
        float v = row[c];
        if (v > best) { best = v; bci = c; }
    }
    // combine 4 lanes; tie-break smallest class index (jnp.argmax = first)
    #pragma unroll
    for (int m = 1; m <= 2; m <<= 1) {
        float ov = __shfl_xor(best, m, 64);
        int   oi = __shfl_xor(bci,  m, 64);
        if (ov > best || (ov == best && oi < bci)) { best = ov; bci = oi; }
    }
    // all 4 lanes of a box now agree on (best, bci)
    bool valid = (bci != 0) && (best >= CONF_T);
    bool pred  = (q == 0) && valid;

    unsigned long long m = __ballot(pred);
    if (m != 0ull) {
        int lane   = threadIdx.x & 63;
        int leader = __ffsll((unsigned long long)m) - 1;
        int base   = 0;
        if (lane == leader) base = atomicAdd(&cnt[b], __popcll(m));
        base = __shfl(base, leader, 64);
        if (pred) {
            int rank = __popcll(m & ((1ull << lane) - 1ull));
            int pos  = base + rank;
            const float* t = row + NCLS;         // [off0..3, acx, acy, aw, ah, v0..3]
            float cx = t[0] * t[8]  * t[6] + t[4];
            float cy = t[1] * t[9]  * t[7] + t[5];
            float w  = expf(t[2] * t[10]) * t[6];
            float h  = expf(t[3] * t[11]) * t[7];
            float4 bx;
            bx.x = (cx - 0.5f * w) * IMG_W;
            bx.y = (cy - 0.5f * h) * IMG_H;
            bx.z = (cx + 0.5f * w) * IMG_W;
            bx.w = (cy + 0.5f * h) * IMG_H;
            size_t g = (size_t)b * NBOX + pos;
            cboxes[g]  = bx;
            cscores[g] = best;
            cclsid[g]  = (float)bci;
        }
    }
}

// ---------------- Kernel 2: greedy NMS over compacted candidates ------------
// One block per image. Fast path (n <= 12288): scores AND boxes live entirely
// in registers -> each round is pure VALU + shuffle reduce, zero memory
// traffic. Overflow tail (rare): scores in LDS, boxes re-read from L2.
// Greedy picks emit in non-increasing score order == top_k(kept, 10).
__global__ __launch_bounds__(K2T) void nms_kernel(
    const float4* __restrict__ cboxes, const float* __restrict__ cscores,
    const float* __restrict__ cclsid, const int* __restrict__ cnt,
    float* __restrict__ out)
{
    __shared__ float ovsc[NPER_OV * K2T];        // 48 KB overflow scores
    __shared__ float pv[16];
    __shared__ int   pi[16];
    __shared__ float bvS;
    __shared__ int   biS;
    int b = blockIdx.x, tid = threadIdx.x;
    int lane = tid & 63, wid = tid >> 6;
    int n = cnt[b];
    const float4* bxp = cboxes  + (size_t)b * NBOX;
    const float*  scp = cscores + (size_t)b * NBOX;

    float  sreg[NPER_R];
    float4 breg[NPER_R];
    #pragma unroll
    for (int j = 0; j < NPER_R; j++) {
        int g = j * K2T + tid;
        bool in = (g < n);
        sreg[j] = in ? scp[g] : -INFINITY;
        breg[j] = in ? bxp[g] : make_float4(0.f, 0.f, 0.f, 0.f);
    }
    bool ovf = (n > CAP_SLOTS);                  // uniform across block
    if (ovf) {
        #pragma unroll
        for (int j = 0; j < NPER_OV; j++) {
            int g = (NPER_R + j) * K2T + tid;
            ovsc[j * K2T + tid] = (g < n) ? scp[g] : -INFINITY;
        }
    }

    float4 qb = make_float4(0.f, 0.f, 0.f, 0.f);
    float  aq = 0.f;
    bool   have_pick = false;

    for (int r = 0; r < NUM_PRED; r++) {
        // fused: suppress vs previous pick + local argmax, single pass
        float v = -INFINITY; int idx = -1;
        #pragma unroll
        for (int j = 0; j < NPER_R; j++) {
            float s = sreg[j];
            if (s > -INFINITY) {
                if (have_pick) {
                    float4 p = breg[j];
                    float iw = fmaxf(fminf(p.z, qb.z) - fmaxf(p.x, qb.x), 0.0f);
                    float ih = fmaxf(fminf(p.w, qb.w) - fmaxf(p.y, qb.y), 0.0f);
                    float inter = iw * ih;
                    float ab = (p.z - p.x) * (p.w - p.y);
                    float iou = inter / (ab + aq - inter + 1e-12f);
                    if (iou > IOU_T) { s = -INFINITY; sreg[j] = s; }
                }
                if (s > v) { v = s; idx = j * K2T + tid; }
            }
        }
        if (ovf) {                               // rare tail: LDS scores + L2 boxes
            #pragma unroll
            for (int j = 0; j < NPER_OV; j++) {
                float s = ovsc[j * K2T + tid];
                if (s > -INFINITY) {
                    int g = (NPER_R + j) * K2T + tid;
                    if (have_pick) {
                        float4 p = bxp[g];
                        float iw = fmaxf(fminf(p.z, qb.z) - fmaxf(p.x, qb.x), 0.0f);
                        float ih = fmaxf(fminf(p.w, qb.w) - fmaxf(p.y, qb.y), 0.0f);
                        float inter = iw * ih;
                        float ab = (p.z - p.x) * (p.w - p.y);
                        float iou = inter / (ab + aq - inter + 1e-12f);
                        if (iou > IOU_T) { s = -INFINITY; ovsc[j * K2T + tid] = s; }
                    }
                    if (s > v) { v = s; idx = g; }
                }
            }
        }
        // wave argmax (ties measure-zero; scores are distinct reals)
        #pragma unroll
        for (int m = 1; m < 64; m <<= 1) {
            float ov = __shfl_xor(v, m, 64);
            int   oi = __shfl_xor(idx, m, 64);
            if (ov > v) { v = ov; idx = oi; }
        }
        if (lane == 0) { pv[wid] = v; pi[wid] = idx; }
        __syncthreads();
        if (wid == 0) {
            float v2 = (lane < 16) ? pv[lane] : -INFINITY;
            int   i2 = (lane < 16) ? pi[lane] : -1;
            #pragma unroll
            for (int m = 1; m < 16; m <<= 1) {
                float ov = __shfl_xor(v2, m, 64);
                int   oi = __shfl_xor(i2, m, 64);
                if (ov > v2) { v2 = ov; i2 = oi; }
            }
            if (lane == 0) { bvS = v2; biS = i2; }
        }
        __syncthreads();
        float bv = bvS; int bi = biS;

        if (!(bv > -INFINITY)) {                 // uniform: exhausted
            if (tid == 0) {
                for (int rr = r; rr < NUM_PRED; rr++) {
                    float* o = out + ((size_t)b * NUM_PRED + rr) * 6;
                    for (int k = 0; k < 6; k++) o[k] = 0.0f;
                }
            }
            return;
        }

        qb = bxp[bi];                            // same addr all lanes: broadcast
        aq = (qb.z - qb.x) * (qb.w - qb.y);
        have_pick = true;
        if (tid == 0) {
            float* o = out + ((size_t)b * NUM_PRED + r) * 6;
            o[0] = cclsid[(size_t)b * NBOX + bi];
            o[1] = bv;
            o[2] = qb.x; o[3] = qb.y; o[4] = qb.z; o[5] = qb.w;
        }
        // no extra barrier needed: next round's pv/pi writes happen after the
        // next scan; this round's pv/pi reads completed before barrier 2.
    }
}

extern "C" void kernel_launch(void* const* d_in, const int* in_sizes, int n_in,
                              void* d_out, int out_size, void* d_ws, size_t ws_size,
                              hipStream_t stream) {
    const float* y = (const float*)d_in[0];
    float* out = (float*)d_out;
    char* ws = (char*)d_ws;
    // ws layout: cboxes (B*NBOX float4) | cscores (B*NBOX f32) | cclsid (B*NBOX f32) | cnt (B i32)
    float4* cboxes  = (float4*)ws;
    float*  cscores = (float*)(ws + (size_t)B * NBOX * sizeof(float4));
    float*  cclsid  = cscores + (size_t)B * NBOX;
    int*    cnt     = (int*)(cclsid + (size_t)B * NBOX);

    hipMemsetAsync(cnt, 0, B * sizeof(int), stream);
    decode_kernel<<<B * NBLK, K1_THREADS, 0, stream>>>(y, cboxes, cscores, cclsid, cnt);
    nms_kernel<<<B, K2T, 0, stream>>>(cboxes, cscores, cclsid, cnt, out);
}

// Round 3
// 446.212 us; speedup vs baseline: 1.9572x; 1.9572x over previous
//
#include <hip/hip_runtime.h>
#include <math.h>

#define B 32
#define NBOX 24564
#define NCLS 81
#define ROWLEN 93
#define CONF_T 0.5f
#define IOU_T 0.35f
#define NUM_PRED 10
#define IMG_W 512.0f
#define IMG_H 512.0f

#define BPB 64                                   // boxes per block in decode
#define K1_THREADS 256
#define NBLK ((NBOX + BPB - 1) / BPB)            // 384 blocks per image
#define NSEG (NBLK * 4)                          // 1536 wave-segments/image, 16 boxes each

#define K2T 1024
#define NPER_R 14                                // register-resident slots/thread
#define CAP_SLOTS (K2T * NPER_R)                 // 14336 fast-path candidates
#define NPER_ALL ((NBOX + K2T - 1) / K2T)        // 24
#define NPER_OV (NPER_ALL - NPER_R)              // 10 overflow slots (global-backed)

// ---------------- Kernel 1: decode + argmax + ATOMIC-FREE compaction --------
// 256 threads / 64 boxes staged via float4. Each WAVE owns a fixed 16-box
// segment: ballot-rank compaction within the wave, count (<=16) written to a
// per-segment byte. No atomics anywhere -> no cross-XCD line ping-pong (the
// round-1 atomicAdd convoy on cnt[] cost 400 us).
__global__ __launch_bounds__(K1_THREADS) void decode_kernel(
    const float* __restrict__ y, float4* __restrict__ cboxes,
    float* __restrict__ cscores, float* __restrict__ cclsid,
    unsigned char* __restrict__ segcnt)
{
    __shared__ float4 lds4[(BPB * ROWLEN) / 4];  // 1488 float4 = 23808 B
    float* lds = (float*)lds4;
    int bid  = blockIdx.x;
    int b    = bid / NBLK;
    int blk  = bid % NBLK;
    int box0 = blk * BPB;
    int nb   = NBOX - box0; if (nb > BPB) nb = BPB;   // 64 or 52 (both %4==0)
    int n4   = (nb * ROWLEN) / 4;
    const float4* src4 = (const float4*)(y + ((size_t)b * NBOX + box0) * ROWLEN);
    for (int k = threadIdx.x; k < n4; k += K1_THREADS)
        lds4[k] = src4[k];
    __syncthreads();

    int q    = threadIdx.x & 3;                  // lane quad within a box
    int bl   = threadIdx.x >> 2;                 // local box index
    int lane = threadIdx.x & 63;
    int wid  = threadIdx.x >> 6;                 // wave id in block (0..3)
    bool active = (bl < nb);                     // whole quads: shfl partners safe
    const float* row = &lds[bl * ROWLEN];

    float best = -INFINITY; int bci = 0x7fffffff;
    if (active) {
        // strided partial argmax; strict '>' keeps first occurrence per lane
        for (int c = q; c < NCLS; c += 4) {
            float v = row[c];
            if (v > best) { best = v; bci = c; }
        }
        // combine 4 lanes; tie-break smallest class index (jnp.argmax = first)
        #pragma unroll
        for (int m = 1; m <= 2; m <<= 1) {
            float ov = __shfl_xor(best, m, 64);
            int   oi = __shfl_xor(bci,  m, 64);
            if (ov > best || (ov == best && oi < bci)) { best = ov; bci = oi; }
        }
    }
    bool pred = active && (q == 0) && (bci != 0) && (best >= CONF_T);
    unsigned long long m = __ballot(pred);
    if (pred) {
        int rank = __popcll(m & ((1ull << lane) - 1ull));
        const float* t = row + NCLS;             // [off0..3, acx, acy, aw, ah, v0..3]
        float cx = t[0] * t[8]  * t[6] + t[4];
        float cy = t[1] * t[9]  * t[7] + t[5];
        float w  = expf(t[2] * t[10]) * t[6];
        float h  = expf(t[3] * t[11]) * t[7];
        float4 bx;
        bx.x = (cx - 0.5f * w) * IMG_W;
        bx.y = (cy - 0.5f * h) * IMG_H;
        bx.z = (cx + 0.5f * w) * IMG_W;
        bx.w = (cy + 0.5f * h) * IMG_H;
        int srci = box0 + wid * 16 + rank;       // compact within wave segment
        size_t g = (size_t)b * NBOX + srci;
        cboxes[g]  = bx;
        cscores[g] = best;
        cclsid[g]  = (float)bci;
    }
    if (lane == 0)
        segcnt[(size_t)b * NSEG + blk * 4 + wid] = (unsigned char)__popcll(m);
}

// binary search: first segment s with pref[s] > g; returns s, *base = pref[s-1]
__device__ __forceinline__ int seg_search(const int* pref, int g, int* base) {
    int lo = 0, hi = NSEG - 1;
    while (lo < hi) { int mid = (lo + hi) >> 1; if (pref[mid] > g) hi = mid; else lo = mid + 1; }
    *base = lo ? pref[lo - 1] : 0;
    return lo;
}

// ---------------- Kernel 2: greedy NMS over compacted candidates ------------
// One block per image. Prefix-scan the 1536 segment counts (LDS), gather the
// ~12.7k candidates into REGISTERS (score + box, 14 slots/thread). Each round:
// fused suppress+argmax, pure VALU + shuffle, zero memory traffic. Overflow
// (n > 14336, ~20 sigma above measured mean) falls back to global-backed slots.
__global__ __launch_bounds__(K2T) void nms_kernel(
    const float4* __restrict__ cboxes, float* __restrict__ cscores,
    const float* __restrict__ cclsid, const unsigned char* __restrict__ segcnt,
    float* __restrict__ out)
{
    __shared__ int   pref[2048];                 // 8 KB: inclusive prefix of counts
    __shared__ float pv[16];
    __shared__ int   pi[16];
    __shared__ float bvS;
    __shared__ int   biS;
    int b = blockIdx.x, tid = threadIdx.x;
    int lane = tid & 63, wid = tid >> 6;
    const float4* bxp = cboxes  + (size_t)b * NBOX;
    float*        scp = cscores + (size_t)b * NBOX;
    const unsigned char* sc8 = segcnt + (size_t)b * NSEG;

    // load counts + Hillis-Steele inclusive scan over 2048 (pad zeros)
    int i1 = tid + 1024;
    pref[tid] = (tid < NSEG) ? (int)sc8[tid] : 0;
    pref[i1]  = (i1  < NSEG) ? (int)sc8[i1]  : 0;
    __syncthreads();
    for (int d = 1; d < 2048; d <<= 1) {
        int v0 = (tid >= d) ? pref[tid - d] : 0;
        int v1 = pref[i1 - d];                   // i1 >= 1024 >= d always
        __syncthreads();
        pref[tid] += v0; pref[i1] += v1;
        __syncthreads();
    }
    int n = pref[NSEG - 1];

    // gather candidates into registers
    float  sreg[NPER_R];
    float4 breg[NPER_R];
    #pragma unroll
    for (int j = 0; j < NPER_R; j++) {
        int g = j * K2T + tid;
        if (g < n) {
            int base; int s = seg_search(pref, g, &base);
            int srci = s * 16 + (g - base);
            sreg[j] = scp[srci];
            breg[j] = bxp[srci];
        } else {
            sreg[j] = -INFINITY;
            breg[j] = make_float4(0.f, 0.f, 0.f, 0.f);
        }
    }
    bool ovf = (n > CAP_SLOTS);                  // uniform across block

    float4 qb = make_float4(0.f, 0.f, 0.f, 0.f);
    float  aq = 0.f;
    bool   have_pick = false;

    for (int r = 0; r < NUM_PRED; r++) {
        // fused: suppress vs previous pick + local argmax, single pass
        float v = -INFINITY; int idx = -1;
        #pragma unroll
        for (int j = 0; j < NPER_R; j++) {
            float s = sreg[j];
            if (s > -INFINITY) {
                if (have_pick) {
                    float4 p = breg[j];
                    float iw = fmaxf(fminf(p.z, qb.z) - fmaxf(p.x, qb.x), 0.0f);
                    float ih = fmaxf(fminf(p.w, qb.w) - fmaxf(p.y, qb.y), 0.0f);
                    float inter = iw * ih;
                    float ab = (p.z - p.x) * (p.w - p.y);
                    float iou = inter / (ab + aq - inter + 1e-12f);
                    if (iou > IOU_T) { s = -INFINITY; sreg[j] = s; }
                }
                if (s > v) { v = s; idx = j * K2T + tid; }
            }
        }
        if (ovf) {                               // never expected; correctness net
            for (int j = 0; j < NPER_OV; j++) {
                int g = (NPER_R + j) * K2T + tid;
                if (g < n) {
                    int base; int sg = seg_search(pref, g, &base);
                    int srci = sg * 16 + (g - base);
                    float s = scp[srci];
                    if (s > -INFINITY) {
                        if (have_pick) {
                            float4 p = bxp[srci];
                            float iw = fmaxf(fminf(p.z, qb.z) - fmaxf(p.x, qb.x), 0.0f);
                            float ih = fmaxf(fminf(p.w, qb.w) - fmaxf(p.y, qb.y), 0.0f);
                            float inter = iw * ih;
                            float ab = (p.z - p.x) * (p.w - p.y);
                            float iou = inter / (ab + aq - inter + 1e-12f);
                            if (iou > IOU_T) { s = -INFINITY; scp[srci] = s; }
                        }
                        if (s > v) { v = s; idx = g; }
                    }
                }
            }
        }
        // wave argmax (ties measure-zero; scores are distinct reals)
        #pragma unroll
        for (int m = 1; m < 64; m <<= 1) {
            float ov = __shfl_xor(v, m, 64);
            int   oi = __shfl_xor(idx, m, 64);
            if (ov > v) { v = ov; idx = oi; }
        }
        if (lane == 0) { pv[wid] = v; pi[wid] = idx; }
        __syncthreads();
        if (wid == 0) {
            float v2 = (lane < 16) ? pv[lane] : -INFINITY;
            int   i2 = (lane < 16) ? pi[lane] : -1;
            #pragma unroll
            for (int m = 1; m < 16; m <<= 1) {
                float ov = __shfl_xor(v2, m, 64);
                int   oi = __shfl_xor(i2, m, 64);
                if (ov > v2) { v2 = ov; i2 = oi; }
            }
            if (lane == 0) { bvS = v2; biS = i2; }
        }
        __syncthreads();
        float bv = bvS; int bi = biS;

        if (!(bv > -INFINITY)) {                 // uniform: exhausted
            if (tid == 0) {
                for (int rr = r; rr < NUM_PRED; rr++) {
                    float* o = out + ((size_t)b * NUM_PRED + rr) * 6;
                    for (int k = 0; k < 6; k++) o[k] = 0.0f;
                }
            }
            return;
        }

        // map compact winner index -> source slot (11 broadcast LDS reads)
        int base; int sg = seg_search(pref, bi, &base);
        int srcp = sg * 16 + (bi - base);
        qb = bxp[srcp];                          // same addr all lanes: broadcast
        aq = (qb.z - qb.x) * (qb.w - qb.y);
        have_pick = true;
        if (tid == 0) {
            float* o = out + ((size_t)b * NUM_PRED + r) * 6;
            o[0] = cclsid[(size_t)b * NBOX + srcp];
            o[1] = bv;
            o[2] = qb.x; o[3] = qb.y; o[4] = qb.z; o[5] = qb.w;
        }
        // no extra barrier needed: next round's pv/pi writes happen after the
        // next scan; this round's pv/pi reads completed before barrier 2.
    }
}

extern "C" void kernel_launch(void* const* d_in, const int* in_sizes, int n_in,
                              void* d_out, int out_size, void* d_ws, size_t ws_size,
                              hipStream_t stream) {
    const float* y = (const float*)d_in[0];
    float* out = (float*)d_out;
    char* ws = (char*)d_ws;
    // ws layout: cboxes (B*NBOX float4) | cscores (B*NBOX f32) | cclsid (B*NBOX f32)
    //          | segcnt (B*NSEG u8)
    float4* cboxes  = (float4*)ws;
    float*  cscores = (float*)(ws + (size_t)B * NBOX * sizeof(float4));
    float*  cclsid  = cscores + (size_t)B * NBOX;
    unsigned char* segcnt = (unsigned char*)(cclsid + (size_t)B * NBOX);

    decode_kernel<<<B * NBLK, K1_THREADS, 0, stream>>>(y, cboxes, cscores, cclsid, segcnt);
    nms_kernel<<<B, K2T, 0, stream>>>(cboxes, cscores, cclsid, segcnt, out);
}